// Round 12
// baseline (81.087 us; speedup 1.0000x reference)
//
#include <hip/hip_runtime.h>
#include <hip/hip_bf16.h>
#include <math.h>

#define NB 1024
#define N 256
#define EPS 1e-6f
#define SQRT_EPS 1e-3f   // sqrt(1e-6)

typedef short bf16x8 __attribute__((ext_vector_type(8)));
typedef float f32x4  __attribute__((ext_vector_type(4)));

__device__ __forceinline__ float fast_rcp(float x) {
    return __builtin_amdgcn_rcpf(x);
}
__device__ __forceinline__ float sigmoidf(float x) {
    return fast_rcp(1.0f + __expf(-x));
}
__device__ __forceinline__ float fast_tanh(float x) {
    float ax = fabsf(x);
    float e  = __expf(2.0f * ax);
    float t  = 1.0f - 2.0f * fast_rcp(e + 1.0f);
    return copysignf(t, x);
}
__device__ __forceinline__ unsigned short to_bf16(float f) {
    __hip_bfloat16 h = __float2bfloat16(f);
    return *(unsigned short*)&h;
}

// ---- prep: convert x (262144 f32) + 6 weight mats (6x65536 f32) to bf16 ----
// out layout (ushort): [0,262144) = xb; then Wd1,Wu1,Wm1,Wd2,Wu2,Wm2.
__global__ __launch_bounds__(256) void prep_kernel(
    const float* __restrict__ x,
    const float* __restrict__ Wd1, const float* __restrict__ Wu1,
    const float* __restrict__ Wm1, const float* __restrict__ Wd2,
    const float* __restrict__ Wu2, const float* __restrict__ Wm2,
    unsigned short* __restrict__ out)
{
    const int fi = blockIdx.x * 256 + threadIdx.x;    // float4 index; 163840 total
    const int base = fi * 4;
    const float* src;
    int off;
    if (base < 262144) { src = x; off = base; }
    else {
        int t = base - 262144;
        int r = t >> 16;
        off = t & 65535;
        src = (r == 0) ? Wd1 : (r == 1) ? Wu1 : (r == 2) ? Wm1
            : (r == 3) ? Wd2 : (r == 4) ? Wu2 : Wm2;
    }
    float4 f = *(const float4*)(src + off);
    ushort4 o;
    o.x = to_bf16(f.x); o.y = to_bf16(f.y); o.z = to_bf16(f.z); o.w = to_bf16(f.w);
    *(ushort4*)(out + base) = o;
}

// ---- MFMA MLP: 64 blocks x 256 threads; block = 16 batch rows.
// Wave w computes neurons [w*64, w*64+64) for all 16 rows.
// mfma_f32_16x16x32_bf16: A/B frag: lane holds (idx=lane&15, k=(lane>>4)*8+e),
// C/D: col=lane&15, row=(lane>>4)*4+reg.
#define H1S 264   // padded LDS row stride (bf16 elems / f32 elems)
__global__ __launch_bounds__(256) void mlp_mfma_kernel(
    const unsigned short* __restrict__ conv,   // xb + 6 weight mats (bf16)
    const float* __restrict__ bd1, const float* __restrict__ bu1,
    const float* __restrict__ bm1, const float* __restrict__ bd2,
    const float* __restrict__ bu2, const float* __restrict__ bm2,
    const float* __restrict__ v,
    float* __restrict__ out_mean, float* __restrict__ out_z,
    float* __restrict__ ws_a, float* __restrict__ ws_tp, float* __restrict__ ws_s)
{
    __shared__ unsigned short h1s[3][16][H1S];   // 25.3 KB (bf16 activations)
    __shared__ float h2f[3][16][H1S];            // 50.7 KB (f32 activated d,u,m)

    const int tid  = threadIdx.x;
    const int l    = tid & 63;
    const int w    = tid >> 6;          // wave 0..3
    const int ml   = l & 15;            // A-row / B-col / C-col lane index
    const int kg   = l >> 4;            // k-group 0..3
    const int b0   = blockIdx.x * 16;

    const unsigned short* xb = conv;
    const unsigned short* Wb = conv + 262144;    // 6 mats of 65536

    // ---- layer 1: A-frags from xb (global, contiguous 16B/lane) ----
    bf16x8 af[8];
    {
        const unsigned short* xrow = xb + (size_t)(b0 + ml) * N;
        #pragma unroll
        for (int kq = 0; kq < 8; ++kq)
            af[kq] = *(const bf16x8*)(xrow + kq * 32 + kg * 8);
    }
    #pragma unroll
    for (int mlp = 0; mlp < 3; ++mlp) {
        const unsigned short* Wl = Wb + (size_t)mlp * 65536;
        f32x4 acc[4] = {{0,0,0,0},{0,0,0,0},{0,0,0,0},{0,0,0,0}};
        #pragma unroll
        for (int kq = 0; kq < 8; ++kq) {
            #pragma unroll
            for (int nt = 0; nt < 4; ++nt) {
                const int n0 = w * 64 + nt * 16;
                bf16x8 bf = *(const bf16x8*)(Wl + (size_t)(n0 + ml) * N + kq * 32 + kg * 8);
                acc[nt] = __builtin_amdgcn_mfma_f32_16x16x32_bf16(af[kq], bf, acc[nt], 0, 0, 0);
            }
        }
        const float* bias = (mlp == 0) ? bd1 : (mlp == 1) ? bu1 : bm1;
        #pragma unroll
        for (int nt = 0; nt < 4; ++nt) {
            const int n = w * 64 + nt * 16 + ml;
            const float bb = bias[n];
            #pragma unroll
            for (int reg = 0; reg < 4; ++reg) {
                const int row = kg * 4 + reg;
                float val = acc[nt][reg] + bb;
                float act = (mlp < 2) ? sigmoidf(val) : fast_tanh(val);
                h1s[mlp][row][n] = to_bf16(act);
            }
        }
    }
    __syncthreads();

    // ---- layer 2: A-frags from h1s (LDS), B from Wb[3+mlp] ----
    #pragma unroll
    for (int mlp = 0; mlp < 3; ++mlp) {
        bf16x8 af2[8];
        #pragma unroll
        for (int kq = 0; kq < 8; ++kq)
            af2[kq] = *(const bf16x8*)&h1s[mlp][ml][kq * 32 + kg * 8];
        const unsigned short* Wl = Wb + (size_t)(3 + mlp) * 65536;
        f32x4 acc[4] = {{0,0,0,0},{0,0,0,0},{0,0,0,0},{0,0,0,0}};
        #pragma unroll
        for (int kq = 0; kq < 8; ++kq) {
            #pragma unroll
            for (int nt = 0; nt < 4; ++nt) {
                const int n0 = w * 64 + nt * 16;
                bf16x8 bf = *(const bf16x8*)(Wl + (size_t)(n0 + ml) * N + kq * 32 + kg * 8);
                acc[nt] = __builtin_amdgcn_mfma_f32_16x16x32_bf16(af2[kq], bf, acc[nt], 0, 0, 0);
            }
        }
        const float* bias = (mlp == 0) ? bd2 : (mlp == 1) ? bu2 : bm2;
        #pragma unroll
        for (int nt = 0; nt < 4; ++nt) {
            const int n = w * 64 + nt * 16 + ml;
            const float bb = bias[n];
            #pragma unroll
            for (int reg = 0; reg < 4; ++reg) {
                const int row = kg * 4 + reg;
                float val = acc[nt][reg] + bb;
                float act = (mlp < 2) ? sigmoidf(val) : fast_tanh(val);
                h2f[mlp][row][n] = act;          // d,u,m activated f32
            }
        }
    }
    __syncthreads();

    // ---- epilogue: wave w owns rows 4w..4w+3; butterfly all-reduce ----
    #pragma unroll
    for (int qi = 0; qi < 4; ++qi) {
        const int r = w * 4 + qi;
        float dd[4], uu[4], vv[4];
        float Su = 0.f, qs = 0.f, Sv = 0.f;
        #pragma unroll
        for (int c = 0; c < 4; ++c) {
            const int n = l + 64 * c;
            dd[c] = h2f[0][r][n];
            uu[c] = h2f[1][r][n];
            vv[c] = v[(size_t)(b0 + r) * N + n];
            Su += uu[c];
            qs += uu[c] * uu[c] * fast_rcp(dd[c]);
            Sv += vv[c];
        }
        #pragma unroll
        for (int off = 1; off < 64; off <<= 1) {
            Su += __shfl_xor(Su, off, 64);
            qs += __shfl_xor(qs, off, 64);
            Sv += __shfl_xor(Sv, off, 64);
        }
        const float utDu  = qs + EPS * Su * Su;
        const float sqeta = rsqrtf(1.0f + utDu);
        const float right = (1.0f - sqeta) / utDu;

        float aC[4], tpC[4], sC[4];
        float sv = 0.f;
        #pragma unroll
        for (int c = 0; c < 4; ++c) {
            const float inv_d = fast_rcp(dd[c]);
            aC[c]  = sqrtf(inv_d + EPS);
            sC[c]  = uu[c] * aC[c] + SQRT_EPS * (Su - uu[c]);
            tpC[c] = right * (uu[c] * inv_d + EPS * Su);
            sv += sC[c] * vv[c];
        }
        #pragma unroll
        for (int off = 1; off < 64; off <<= 1)
            sv += __shfl_xor(sv, off, 64);

        #pragma unroll
        for (int c = 0; c < 4; ++c) {
            const int n = l + 64 * c;
            const size_t row = (size_t)(b0 + r) * N + n;
            const float m_ = h2f[2][r][n];
            out_mean[row] = m_;
            out_z[row]    = SQRT_EPS * Sv + (aC[c] - SQRT_EPS) * vv[c] - tpC[c] * sv + m_;
            ws_a[row]     = aC[c];
            ws_tp[row]    = tpC[c];
            ws_s[row]     = sC[c];
        }
    }
}

// r_R4 (BYTE-IDENTICAL to R4's writer, ~38.9 us / 6.9 TB/s).
__global__ __launch_bounds__(256) void r_kernel(
    const float* __restrict__ ws_a, const float* __restrict__ ws_tp,
    const float* __restrict__ ws_s, float* __restrict__ R)
{
    __shared__ float s_lds[N];
    __shared__ float a_lds[64];
    __shared__ float tp_lds[64];

    const int tid   = threadIdx.x;
    const int b     = blockIdx.x >> 2;
    const int chunk = blockIdx.x & 3;
    const int ibase = chunk * 64;

    s_lds[tid] = ws_s[(size_t)b * N + tid];
    if (tid < 64) {
        a_lds[tid]  = ws_a[(size_t)b * N + ibase + tid];
        tp_lds[tid] = ws_tp[(size_t)b * N + ibase + tid];
    }
    __syncthreads();

    const int j4 = tid & 63;
    const int il = tid >> 6;
    const float4 sv = ((const float4*)s_lds)[j4];
    float4* Rb = (float4*)(R + (size_t)b * N * N);
    const int jb = j4 * 4;

    #pragma unroll
    for (int it = 0; it < 16; ++it) {
        const int i_loc = it * 4 + il;
        const int i     = ibase + i_loc;
        const float a   = a_lds[i_loc];
        const float tp  = tp_lds[i_loc];
        float4 o;
        o.x = SQRT_EPS - tp * sv.x;
        o.y = SQRT_EPS - tp * sv.y;
        o.z = SQRT_EPS - tp * sv.z;
        o.w = SQRT_EPS - tp * sv.w;
        if (i >= jb && i < jb + 4) {
            const float add = a - SQRT_EPS;
            if      (i == jb)     o.x += add;
            else if (i == jb + 1) o.y += add;
            else if (i == jb + 2) o.z += add;
            else                  o.w += add;
        }
        Rb[(size_t)i * 64 + j4] = o;
    }
}

extern "C" void kernel_launch(void* const* d_in, const int* in_sizes, int n_in,
                              void* d_out, int out_size, void* d_ws, size_t ws_size,
                              hipStream_t stream) {
    const float* x   = (const float*)d_in[0];
    const float* Wd1 = (const float*)d_in[1];
    const float* bd1 = (const float*)d_in[2];
    const float* Wd2 = (const float*)d_in[3];
    const float* bd2 = (const float*)d_in[4];
    const float* Wu1 = (const float*)d_in[5];
    const float* bu1 = (const float*)d_in[6];
    const float* Wu2 = (const float*)d_in[7];
    const float* bu2 = (const float*)d_in[8];
    const float* Wm1 = (const float*)d_in[9];
    const float* bm1 = (const float*)d_in[10];
    const float* Wm2 = (const float*)d_in[11];
    const float* bm2 = (const float*)d_in[12];
    const float* v   = (const float*)d_in[13];

    float* out      = (float*)d_out;
    float* out_mean = out;                                   // [1024,256]
    float* R        = out + (size_t)NB * N;                  // [1024,256,256]
    float* out_z    = R + (size_t)NB * N * N;                // [1024,256]

    float* wsf   = (float*)d_ws;
    float* ws_a  = wsf;                            // [1024,256]
    float* ws_tp = wsf + (size_t)NB * N;           // [1024,256]
    float* ws_s  = wsf + (size_t)2 * NB * N;       // [1024,256]
    unsigned short* conv = (unsigned short*)(wsf + (size_t)3 * NB * N);  // bf16 area

    prep_kernel<<<640, 256, 0, stream>>>(x, Wd1, Wu1, Wm1, Wd2, Wu2, Wm2, conv);

    mlp_mfma_kernel<<<NB / 16, 256, 0, stream>>>(
        conv, bd1, bu1, bm1, bd2, bu2, bm2, v,
        out_mean, out_z, ws_a, ws_tp, ws_s);

    r_kernel<<<NB * 4, 256, 0, stream>>>(ws_a, ws_tp, ws_s, R);
}

// Round 13
// 70.401 us; speedup vs baseline: 1.1518x; 1.1518x over previous
//
#include <hip/hip_runtime.h>
#include <hip/hip_bf16.h>
#include <math.h>

#define NB 1024
#define N 256
#define EPS 1e-6f
#define SQRT_EPS 1e-3f   // sqrt(1e-6)

typedef short bf16x8 __attribute__((ext_vector_type(8)));
typedef float f32x4  __attribute__((ext_vector_type(4)));

__device__ __forceinline__ float fast_rcp(float x) {
    return __builtin_amdgcn_rcpf(x);
}
__device__ __forceinline__ float sigmoidf(float x) {
    return fast_rcp(1.0f + __expf(-x));
}
__device__ __forceinline__ float fast_tanh(float x) {
    float ax = fabsf(x);
    float e  = __expf(2.0f * ax);
    float t  = 1.0f - 2.0f * fast_rcp(e + 1.0f);
    return copysignf(t, x);
}
__device__ __forceinline__ unsigned short to_bf16(float f) {
    __hip_bfloat16 h = __float2bfloat16(f);
    return *(unsigned short*)&h;
}

// ---- prep: convert 6 weight mats (6x65536 f32) to bf16 ----
__global__ __launch_bounds__(256) void prep_kernel(
    const float* __restrict__ Wd1, const float* __restrict__ Wu1,
    const float* __restrict__ Wm1, const float* __restrict__ Wd2,
    const float* __restrict__ Wu2, const float* __restrict__ Wm2,
    unsigned short* __restrict__ out)
{
    const int fi = blockIdx.x * 256 + threadIdx.x;   // float4 idx; 98304 total
    const int r  = fi >> 14;                          // matrix 0..5
    const int off = (fi & 16383) * 4;
    const float* src = (r == 0) ? Wd1 : (r == 1) ? Wu1 : (r == 2) ? Wm1
                     : (r == 3) ? Wd2 : (r == 4) ? Wu2 : Wm2;
    float4 f = *(const float4*)(src + off);
    ushort4 o;
    o.x = to_bf16(f.x); o.y = to_bf16(f.y); o.z = to_bf16(f.z); o.w = to_bf16(f.w);
    *(ushort4*)(out + r * 65536 + off) = o;
}

// ---- layer 1: grid 256 = 64 row-tiles x 4 col-tiles; 4 waves/block.
// Wave w: neurons [ct*64 + w*16, +16) for 16 batch rows. A = x (converted
// in-kernel), B = W1 bf16. mfma_f32_16x16x32_bf16; C: col=lane&15 (neuron),
// row = (lane>>4)*4 + reg (batch row). Writes h1 bf16 [3][1024][256].
__global__ __launch_bounds__(256) void l1_kernel(
    const float* __restrict__ x, const unsigned short* __restrict__ Wb,
    const float* __restrict__ bd1, const float* __restrict__ bu1,
    const float* __restrict__ bm1, unsigned short* __restrict__ h1g)
{
    const int tid = threadIdx.x;
    const int w   = tid >> 6;
    const int l   = tid & 63;
    const int ml  = l & 15;
    const int kg  = l >> 4;
    const int b0  = (blockIdx.x >> 2) * 16;
    const int n0  = (blockIdx.x & 3) * 64 + w * 16;

    // A-frags: convert x rows on the fly
    bf16x8 af[8];
    {
        const float* xrow = x + (size_t)(b0 + ml) * N;
        #pragma unroll
        for (int kq = 0; kq < 8; ++kq) {
            float4 f0 = *(const float4*)(xrow + kq * 32 + kg * 8);
            float4 f1 = *(const float4*)(xrow + kq * 32 + kg * 8 + 4);
            bf16x8 a;
            a[0] = (short)to_bf16(f0.x); a[1] = (short)to_bf16(f0.y);
            a[2] = (short)to_bf16(f0.z); a[3] = (short)to_bf16(f0.w);
            a[4] = (short)to_bf16(f1.x); a[5] = (short)to_bf16(f1.y);
            a[6] = (short)to_bf16(f1.z); a[7] = (short)to_bf16(f1.w);
            af[kq] = a;
        }
    }
    #pragma unroll
    for (int mlp = 0; mlp < 3; ++mlp) {
        const unsigned short* Wl = Wb + (size_t)mlp * 65536;
        f32x4 acc = {0.f, 0.f, 0.f, 0.f};
        #pragma unroll
        for (int kq = 0; kq < 8; ++kq) {
            bf16x8 bf = *(const bf16x8*)(Wl + (size_t)(n0 + ml) * N + kq * 32 + kg * 8);
            acc = __builtin_amdgcn_mfma_f32_16x16x32_bf16(af[kq], bf, acc, 0, 0, 0);
        }
        const float* bias = (mlp == 0) ? bd1 : (mlp == 1) ? bu1 : bm1;
        const int n = n0 + ml;
        const float bb = bias[n];
        #pragma unroll
        for (int reg = 0; reg < 4; ++reg) {
            const int row = b0 + kg * 4 + reg;
            float val = acc[reg] + bb;
            float act = (mlp < 2) ? sigmoidf(val) : fast_tanh(val);
            h1g[(size_t)mlp * (NB * N) + (size_t)row * N + n] = to_bf16(act);
        }
    }
}

// ---- layer 2: same geometry; A from h1g (bf16), B = W2. Writes h2 f32.
__global__ __launch_bounds__(256) void l2_kernel(
    const unsigned short* __restrict__ h1g, const unsigned short* __restrict__ Wb,
    const float* __restrict__ bd2, const float* __restrict__ bu2,
    const float* __restrict__ bm2, float* __restrict__ h2g)
{
    const int tid = threadIdx.x;
    const int w   = tid >> 6;
    const int l   = tid & 63;
    const int ml  = l & 15;
    const int kg  = l >> 6 == 0 ? (l >> 4) : (l >> 4);   // kg = l>>4
    const int b0  = (blockIdx.x >> 2) * 16;
    const int n0  = (blockIdx.x & 3) * 64 + w * 16;

    #pragma unroll
    for (int mlp = 0; mlp < 3; ++mlp) {
        const unsigned short* arow = h1g + (size_t)mlp * (NB * N) + (size_t)(b0 + ml) * N;
        bf16x8 af[8];
        #pragma unroll
        for (int kq = 0; kq < 8; ++kq)
            af[kq] = *(const bf16x8*)(arow + kq * 32 + (l >> 4) * 8);
        const unsigned short* Wl = Wb + (size_t)(3 + mlp) * 65536;
        f32x4 acc = {0.f, 0.f, 0.f, 0.f};
        #pragma unroll
        for (int kq = 0; kq < 8; ++kq) {
            bf16x8 bf = *(const bf16x8*)(Wl + (size_t)(n0 + ml) * N + kq * 32 + (l >> 4) * 8);
            acc = __builtin_amdgcn_mfma_f32_16x16x32_bf16(af[kq], bf, acc, 0, 0, 0);
        }
        const float* bias = (mlp == 0) ? bd2 : (mlp == 1) ? bu2 : bm2;
        const int n = n0 + ml;
        const float bb = bias[n];
        #pragma unroll
        for (int reg = 0; reg < 4; ++reg) {
            const int row = b0 + (l >> 4) * 4 + reg;
            float val = acc[reg] + bb;
            float act = (mlp < 2) ? sigmoidf(val) : fast_tanh(val);
            h2g[(size_t)mlp * (NB * N) + (size_t)row * N + n] = act;
        }
    }
}

// ---- epilogue: 256 blocks x 4 waves; wave = one batch row.
__global__ __launch_bounds__(256) void epi_kernel(
    const float* __restrict__ h2g, const float* __restrict__ v,
    float* __restrict__ out_mean, float* __restrict__ out_z,
    float* __restrict__ ws_a, float* __restrict__ ws_tp, float* __restrict__ ws_s)
{
    const int tid = threadIdx.x;
    const int w   = tid >> 6;
    const int l   = tid & 63;
    const int row = blockIdx.x * 4 + w;

    float dd[4], uu[4], vv[4];
    float Su = 0.f, qs = 0.f, Sv = 0.f;
    #pragma unroll
    for (int c = 0; c < 4; ++c) {
        const int n = l + 64 * c;
        dd[c] = h2g[(size_t)0 * (NB * N) + (size_t)row * N + n];
        uu[c] = h2g[(size_t)1 * (NB * N) + (size_t)row * N + n];
        vv[c] = v[(size_t)row * N + n];
        Su += uu[c];
        qs += uu[c] * uu[c] * fast_rcp(dd[c]);
        Sv += vv[c];
    }
    #pragma unroll
    for (int off = 1; off < 64; off <<= 1) {
        Su += __shfl_xor(Su, off, 64);
        qs += __shfl_xor(qs, off, 64);
        Sv += __shfl_xor(Sv, off, 64);
    }
    const float utDu  = qs + EPS * Su * Su;
    const float sqeta = rsqrtf(1.0f + utDu);
    const float right = (1.0f - sqeta) / utDu;

    float aC[4], tpC[4], sC[4];
    float sv = 0.f;
    #pragma unroll
    for (int c = 0; c < 4; ++c) {
        const float inv_d = fast_rcp(dd[c]);
        aC[c]  = sqrtf(inv_d + EPS);
        sC[c]  = uu[c] * aC[c] + SQRT_EPS * (Su - uu[c]);
        tpC[c] = right * (uu[c] * inv_d + EPS * Su);
        sv += sC[c] * vv[c];
    }
    #pragma unroll
    for (int off = 1; off < 64; off <<= 1)
        sv += __shfl_xor(sv, off, 64);

    #pragma unroll
    for (int c = 0; c < 4; ++c) {
        const int n = l + 64 * c;
        const size_t idx = (size_t)row * N + n;
        const float m_ = h2g[(size_t)2 * (NB * N) + idx];
        out_mean[idx] = m_;
        out_z[idx]    = SQRT_EPS * Sv + (aC[c] - SQRT_EPS) * vv[c] - tpC[c] * sv + m_;
        ws_a[idx]     = aC[c];
        ws_tp[idx]    = tpC[c];
        ws_s[idx]     = sC[c];
    }
}

// r_R4 (BYTE-IDENTICAL: ~38.9 us / 6.9 TB/s — at write roofline).
__global__ __launch_bounds__(256) void r_kernel(
    const float* __restrict__ ws_a, const float* __restrict__ ws_tp,
    const float* __restrict__ ws_s, float* __restrict__ R)
{
    __shared__ float s_lds[N];
    __shared__ float a_lds[64];
    __shared__ float tp_lds[64];

    const int tid   = threadIdx.x;
    const int b     = blockIdx.x >> 2;
    const int chunk = blockIdx.x & 3;
    const int ibase = chunk * 64;

    s_lds[tid] = ws_s[(size_t)b * N + tid];
    if (tid < 64) {
        a_lds[tid]  = ws_a[(size_t)b * N + ibase + tid];
        tp_lds[tid] = ws_tp[(size_t)b * N + ibase + tid];
    }
    __syncthreads();

    const int j4 = tid & 63;
    const int il = tid >> 6;
    const float4 sv = ((const float4*)s_lds)[j4];
    float4* Rb = (float4*)(R + (size_t)b * N * N);
    const int jb = j4 * 4;

    #pragma unroll
    for (int it = 0; it < 16; ++it) {
        const int i_loc = it * 4 + il;
        const int i     = ibase + i_loc;
        const float a   = a_lds[i_loc];
        const float tp  = tp_lds[i_loc];
        float4 o;
        o.x = SQRT_EPS - tp * sv.x;
        o.y = SQRT_EPS - tp * sv.y;
        o.z = SQRT_EPS - tp * sv.z;
        o.w = SQRT_EPS - tp * sv.w;
        if (i >= jb && i < jb + 4) {
            const float add = a - SQRT_EPS;
            if      (i == jb)     o.x += add;
            else if (i == jb + 1) o.y += add;
            else if (i == jb + 2) o.z += add;
            else                  o.w += add;
        }
        Rb[(size_t)i * 64 + j4] = o;
    }
}

extern "C" void kernel_launch(void* const* d_in, const int* in_sizes, int n_in,
                              void* d_out, int out_size, void* d_ws, size_t ws_size,
                              hipStream_t stream) {
    const float* x   = (const float*)d_in[0];
    const float* Wd1 = (const float*)d_in[1];
    const float* bd1 = (const float*)d_in[2];
    const float* Wd2 = (const float*)d_in[3];
    const float* bd2 = (const float*)d_in[4];
    const float* Wu1 = (const float*)d_in[5];
    const float* bu1 = (const float*)d_in[6];
    const float* Wu2 = (const float*)d_in[7];
    const float* bu2 = (const float*)d_in[8];
    const float* Wm1 = (const float*)d_in[9];
    const float* bm1 = (const float*)d_in[10];
    const float* Wm2 = (const float*)d_in[11];
    const float* bm2 = (const float*)d_in[12];
    const float* v   = (const float*)d_in[13];

    float* out      = (float*)d_out;
    float* out_mean = out;                                   // [1024,256]
    float* R        = out + (size_t)NB * N;                  // [1024,256,256]
    float* out_z    = R + (size_t)NB * N * N;                // [1024,256]

    float* wsf   = (float*)d_ws;
    float* ws_a  = wsf;                            // [1024,256] f32
    float* ws_tp = wsf + (size_t)NB * N;
    float* ws_s  = wsf + (size_t)2 * NB * N;
    unsigned short* Wb  = (unsigned short*)(wsf + (size_t)3 * NB * N);  // 6x65536 bf16
    unsigned short* h1g = Wb + 6 * 65536;                               // 3x1024x256 bf16
    float* h2g = (float*)(h1g + 3 * NB * N);                            // 3x1024x256 f32

    prep_kernel<<<384, 256, 0, stream>>>(Wd1, Wu1, Wm1, Wd2, Wu2, Wm2, Wb);

    l1_kernel<<<256, 256, 0, stream>>>(x, Wb, bd1, bu1, bm1, h1g);
    l2_kernel<<<256, 256, 0, stream>>>(h1g, Wb, bd2, bu2, bm2, h2g);
    epi_kernel<<<256, 256, 0, stream>>>(h2g, v, out_mean, out_z, ws_a, ws_tp, ws_s);

    r_kernel<<<NB * 4, 256, 0, stream>>>(ws_a, ws_tp, ws_s, R);
}